// Round 6
// baseline (245.766 us; speedup 1.0000x reference)
//
#include <hip/hip_runtime.h>
#include <stdint.h>

#define L_DIM 1024
#define N_DIM 32
#define C_DIM 512
#define M_DIM (L_DIM * N_DIM)   // 32768 rows for the GEMMs
#define EPS_BN 1e-5f

typedef __attribute__((ext_vector_type(8))) short bf16x8;
typedef __attribute__((ext_vector_type(4))) float f32x4;

__device__ __forceinline__ unsigned short f2bf(float f) {
  union { float f; unsigned int u; } a; a.f = f;
  unsigned int u = a.u;
  return (unsigned short)((u + 0x7FFFu + ((u >> 16) & 1u)) >> 16); // RNE
}
__device__ __forceinline__ float bf2f(unsigned short h) {
  union { float f; unsigned int u; } a; a.u = ((unsigned int)h) << 16;
  return a.f;
}

__device__ __forceinline__ void gl16(const void* g, void* l) {
  __builtin_amdgcn_global_load_lds(
      (const __attribute__((address_space(1))) unsigned int*)g,
      (__attribute__((address_space(3))) unsigned int*)l, 16, 0, 0);
}

// ---------------- split fp32 -> bf16 hi/lo: x, W1, W2 in one kernel ----------------
__global__ void k_split_all(const float* __restrict__ x, const float* __restrict__ W1,
                            const float* __restrict__ W2,
                            unsigned short* __restrict__ Ahi, unsigned short* __restrict__ Alo,
                            unsigned short* __restrict__ W1hi, unsigned short* __restrict__ W1lo,
                            unsigned short* __restrict__ W2hi, unsigned short* __restrict__ W2lo) {
  const int NX = M_DIM * C_DIM / 4;      // 4,194,304 float4
  const int NW = C_DIM * C_DIM / 4;      // 65,536 float4
  int i = blockIdx.x * 256 + threadIdx.x;
  int stride = gridDim.x * 256;
  for (; i < NX + 2 * NW; i += stride) {
    const float4* src; unsigned short* dh; unsigned short* dl; int j;
    if (i < NX)            { src = (const float4*)x;  dh = Ahi;  dl = Alo;  j = i; }
    else if (i < NX + NW)  { src = (const float4*)W1; dh = W1hi; dl = W1lo; j = i - NX; }
    else                   { src = (const float4*)W2; dh = W2hi; dl = W2lo; j = i - NX - NW; }
    float4 v = src[j];
    ushort4 h, l;
    h.x = f2bf(v.x); l.x = f2bf(v.x - bf2f(h.x));
    h.y = f2bf(v.y); l.y = f2bf(v.y - bf2f(h.y));
    h.z = f2bf(v.z); l.z = f2bf(v.z - bf2f(h.z));
    h.w = f2bf(v.w); l.w = f2bf(v.w - bf2f(h.w));
    ((ushort4*)dh)[j] = h;
    ((ushort4*)dl)[j] = l;
  }
}

// ---------------- bf16x3 MFMA GEMM: C = A * B^T + bias, fused BN stats ----------------
// 256x256 tile, BK=32, 512 threads = 8 waves (2M x 4N), wave-tile 128x64.
// 6-phase K-step (16 MFMA/phase) with per-phase barrier pairs + setprio (T3/T5);
// double-buffered 128KB LDS, counted vmcnt(8) once per K-step (T4), STAGE after last phase.
// Grid = 256 blocks = 1 block/CU. XCD swizzle: bn pair of each bm on same XCD.
__global__ __launch_bounds__(512, 2)
void k_gemm(const unsigned short* __restrict__ Ahi, const unsigned short* __restrict__ Alo,
            const unsigned short* __restrict__ Bhi, const unsigned short* __restrict__ Blo,
            const float* __restrict__ bias, float* __restrict__ C,
            float* __restrict__ gsum, float* __restrict__ gsq) {
  const int K = C_DIM;
  int d = blockIdx.x;
  int xcd = d & 7;
  int q = d >> 3;                  // 0..31
  int bm = xcd * 16 + (q >> 1);    // 0..127
  int bn = q & 1;                  // 0..1

  __shared__ unsigned short lds[2][32768];   // 128 KB total

  int tid  = threadIdx.x;
  int lane = tid & 63;
  int wave = tid >> 6;
  int wm = wave >> 2;              // 0..1
  int wn = wave & 3;               // 0..3
  int lr = lane & 15;
  int lk = lane >> 4;

  f32x4 acc[8][4];
#pragma unroll
  for (int i = 0; i < 8; ++i)
#pragma unroll
    for (int j = 0; j < 4; ++j) acc[i][j] = (f32x4){0.f, 0.f, 0.f, 0.f};

  const int ra0 = tid & 255, ka0 = (tid >> 8) & 3;
  const int ra1 = (tid + 512) & 255, ka1 = ((tid + 512) >> 8) & 3;
  const int oa0 = (bm * 256 + ra0) * K + ka0 * 8;
  const int oa1 = (bm * 256 + ra1) * K + ka1 * 8;
  const int ob0 = (bn * 256 + ra0) * K + ka0 * 8;
  const int ob1 = (bn * 256 + ra1) * K + ka1 * 8;

#define STAGE(buf, kk)                                          \
  do {                                                          \
    unsigned short* Lb = lds[buf];                              \
    gl16(Ahi + oa0 + (kk), Lb + (tid) * 8);                     \
    gl16(Ahi + oa1 + (kk), Lb + (tid + 512) * 8);               \
    gl16(Alo + oa0 + (kk), Lb + (tid + 1024) * 8);              \
    gl16(Alo + oa1 + (kk), Lb + (tid + 1536) * 8);              \
    gl16(Bhi + ob0 + (kk), Lb + (tid + 2048) * 8);              \
    gl16(Bhi + ob1 + (kk), Lb + (tid + 2560) * 8);              \
    gl16(Blo + ob0 + (kk), Lb + (tid + 3072) * 8);              \
    gl16(Blo + ob1 + (kk), Lb + (tid + 3584) * 8);              \
  } while (0)

  // one phase: {ds_read ops} barrier ; lgkm0 ; prio1 16xMFMA prio0 ; barrier
#define PH_SYNC()                                               \
    __builtin_amdgcn_s_barrier();                               \
    asm volatile("s_waitcnt lgkmcnt(0)" ::: "memory");          \
    __builtin_amdgcn_sched_barrier(0);                          \
    __builtin_amdgcn_s_setprio(1)
#define PH_END()                                                \
    __builtin_amdgcn_s_setprio(0);                              \
    __builtin_amdgcn_s_barrier()
#define MFMA16(AV, BV, IOFF)                                    \
    _Pragma("unroll")                                           \
    for (int i = 0; i < 4; ++i)                                 \
      _Pragma("unroll")                                         \
      for (int j = 0; j < 4; ++j)                               \
        acc[(IOFF) + i][j] = __builtin_amdgcn_mfma_f32_16x16x32_bf16(AV[i], BV[j], acc[(IOFF) + i][j], 0, 0, 0)

#define KSTEP(buf)                                                            \
  do {                                                                        \
    const unsigned short* Lb = lds[buf];                                      \
    bf16x8 bh[4], bl[4], a0[4], a1[4];                                        \
    /* P1: ah[0-3], bh; ah0-3 x bh */                                         \
    _Pragma("unroll")                                                         \
    for (int j = 0; j < 4; ++j)                                               \
      bh[j] = *(const bf16x8*)(Lb + 16384 + (lk * 256 + wn * 64 + j * 16 + lr) * 8); \
    _Pragma("unroll")                                                         \
    for (int i = 0; i < 4; ++i)                                               \
      a0[i] = *(const bf16x8*)(Lb + (lk * 256 + wm * 128 + i * 16 + lr) * 8); \
    PH_SYNC();                                                                \
    MFMA16(a0, bh, 0);                                                        \
    PH_END();                                                                 \
    /* P2: bl; ah0-3 x bl */                                                  \
    _Pragma("unroll")                                                         \
    for (int j = 0; j < 4; ++j)                                               \
      bl[j] = *(const bf16x8*)(Lb + 24576 + (lk * 256 + wn * 64 + j * 16 + lr) * 8); \
    PH_SYNC();                                                                \
    MFMA16(a0, bl, 0);                                                        \
    PH_END();                                                                 \
    /* P3: ah[4-7]; ah4-7 x bh */                                             \
    _Pragma("unroll")                                                         \
    for (int i = 0; i < 4; ++i)                                               \
      a1[i] = *(const bf16x8*)(Lb + (lk * 256 + wm * 128 + (4 + i) * 16 + lr) * 8); \
    PH_SYNC();                                                                \
    MFMA16(a1, bh, 4);                                                        \
    PH_END();                                                                 \
    /* P4: (no reads); ah4-7 x bl */                                          \
    PH_SYNC();                                                                \
    MFMA16(a1, bl, 4);                                                        \
    PH_END();                                                                 \
    /* P5: al[0-3]; al0-3 x bh */                                             \
    _Pragma("unroll")                                                         \
    for (int i = 0; i < 4; ++i)                                               \
      a0[i] = *(const bf16x8*)(Lb + 8192 + (lk * 256 + wm * 128 + i * 16 + lr) * 8); \
    PH_SYNC();                                                                \
    MFMA16(a0, bh, 0);                                                        \
    PH_END();                                                                 \
    /* P6: al[4-7]; al4-7 x bh */                                             \
    _Pragma("unroll")                                                         \
    for (int i = 0; i < 4; ++i)                                               \
      a1[i] = *(const bf16x8*)(Lb + 8192 + (lk * 256 + wm * 128 + (4 + i) * 16 + lr) * 8); \
    PH_SYNC();                                                                \
    MFMA16(a1, bh, 4);                                                        \
    PH_END();                                                                 \
  } while (0)

  const int nt = K >> 5;                       // 16 K-steps
  STAGE(0, 0);
  STAGE(1, 32);

  for (int t = 0; t < nt - 1; ++t) {
    asm volatile("s_waitcnt vmcnt(8)" ::: "memory");   // tile t landed; t+1 in flight
    __builtin_amdgcn_sched_barrier(0);
    __builtin_amdgcn_s_barrier();
    KSTEP(t & 1);
    if (t < nt - 2) STAGE(t & 1, (t + 2) << 5);        // after last-phase barrier: buf free
  }
  asm volatile("s_waitcnt vmcnt(0)" ::: "memory");
  __builtin_amdgcn_sched_barrier(0);
  __builtin_amdgcn_s_barrier();
  KSTEP((nt - 1) & 1);

  // epilogue: C/D layout col = lane&15, row = (lane>>4)*4 + r; fused bias + BN partial stats
#pragma unroll
  for (int nj = 0; nj < 4; ++nj) {
    int gn = bn * 256 + wn * 64 + nj * 16 + lr;
    float bv = bias[gn];
    float s = 0.f, qq = 0.f;
#pragma unroll
    for (int mi = 0; mi < 8; ++mi) {
      int gm = bm * 256 + wm * 128 + mi * 16 + (lk << 2);
#pragma unroll
      for (int r = 0; r < 4; ++r) {
        float v = acc[mi][nj][r] + bv;
        C[(gm + r) * C_DIM + gn] = v;
        s += v; qq += v * v;
      }
    }
    s  += __shfl_xor(s, 16);  qq += __shfl_xor(qq, 16);
    s  += __shfl_xor(s, 32);  qq += __shfl_xor(qq, 32);
    if (lk == 0) {
      atomicAdd(&gsum[gn], s);
      atomicAdd(&gsq[gn], qq);
    }
  }
#undef STAGE
#undef KSTEP
#undef PH_SYNC
#undef PH_END
#undef MFMA16
}

// ---------------- parallel-scan IndRNN ----------------
// h_t = max(x_t + u h_{t-1}, 0). Maps h -> max(A + B h, M) form a monoid (B >= 0):
//   (A2,B2,M2) o (A1,B1,M1) = (A2 + B2*A1, B2*B1, max(A2 + B2*M1, M2))
// Block = 1024 threads = 16 waves; wave w owns L-rows [64w,64w+64) of 64 chains (lanes).
// Phase1: segment triple. Phase2: LDS prefix compose. Phase3: exact replay.

__global__ __launch_bounds__(1024, 4)
void k_indrnn_split(const float* __restrict__ y,
                    const float* __restrict__ gsum, const float* __restrict__ gsq,
                    const float* __restrict__ g, const float* __restrict__ be,
                    const float* __restrict__ u,
                    unsigned short* __restrict__ hhi, unsigned short* __restrict__ hlo) {
  __shared__ float tA[1024], tB[1024], tM[1024];
  int lane = threadIdx.x & 63;
  int w = threadIdx.x >> 6;                 // segment 0..15
  int chain = blockIdx.x * 64 + lane;       // (n,c) flat index
  int c = chain & 511;
  float m  = gsum[c] * (1.0f / (float)M_DIM);
  float vv = gsq[c]  * (1.0f / (float)M_DIM) - m * m;
  float sc = g[c] * rsqrtf(vv + EPS_BN);
  float sh = be[c] - m * sc;
  float uu = u[c];
  const float* py = y + chain;
  const int base = w * 64;

  float A = 0.f, Bc = 1.f, Mx = 0.f;
  for (int c0 = 0; c0 < 64; c0 += 16) {
    float vb[16];
#pragma unroll
    for (int i = 0; i < 16; ++i) vb[i] = py[(base + c0 + i) * 16384];
#pragma unroll
    for (int i = 0; i < 16; ++i) {
      float xt = fmaf(vb[i], sc, sh);
      A  = fmaf(uu, A, xt);
      Mx = fmaxf(fmaf(uu, Mx, xt), 0.f);
      Bc *= uu;
    }
  }
  tA[w * 64 + lane] = A; tB[w * 64 + lane] = Bc; tM[w * 64 + lane] = Mx;
  __syncthreads();

  float pA = 0.f, pM = 0.f;
  for (int s = 0; s < w; ++s) {
    float a = tA[s * 64 + lane], b = tB[s * 64 + lane], mm = tM[s * 64 + lane];
    pA = fmaf(b, pA, a);
    pM = fmaxf(fmaf(b, pM, a), mm);
  }
  float h = fmaxf(pA, pM);        // h_start for this segment (h0 = 0)

  unsigned short* ph = hhi + chain;
  unsigned short* pl = hlo + chain;
  for (int c0 = 0; c0 < 64; c0 += 16) {
    float vb[16];
#pragma unroll
    for (int i = 0; i < 16; ++i) vb[i] = py[(base + c0 + i) * 16384];
#pragma unroll
    for (int i = 0; i < 16; ++i) {
      float xt = fmaf(vb[i], sc, sh);
      h = fmaxf(fmaf(uu, h, xt), 0.f);
      unsigned short hb = f2bf(h);
      int off = (base + c0 + i) * 16384;
      ph[off] = hb;
      pl[off] = f2bf(h - bf2f(hb));
    }
  }
}

__global__ __launch_bounds__(1024, 4)
void k_indrnn_res(float* __restrict__ y, const float* __restrict__ x,
                  const float* __restrict__ gsum, const float* __restrict__ gsq,
                  const float* __restrict__ g, const float* __restrict__ be,
                  const float* __restrict__ u) {
  __shared__ float tA[1024], tB[1024], tM[1024];
  int lane = threadIdx.x & 63;
  int w = threadIdx.x >> 6;
  int chain = blockIdx.x * 64 + lane;
  int c = chain & 511;
  float m  = gsum[c] * (1.0f / (float)M_DIM);
  float vv = gsq[c]  * (1.0f / (float)M_DIM) - m * m;
  float sc = g[c] * rsqrtf(vv + EPS_BN);
  float sh = be[c] - m * sc;
  float uu = u[c];
  float* py = y + chain;
  const float* px = x + chain;
  const int base = w * 64;

  float A = 0.f, Bc = 1.f, Mx = 0.f;
  for (int c0 = 0; c0 < 64; c0 += 16) {
    float vb[16];
#pragma unroll
    for (int i = 0; i < 16; ++i) vb[i] = py[(base + c0 + i) * 16384];
#pragma unroll
    for (int i = 0; i < 16; ++i) {
      float xt = fmaf(vb[i], sc, sh);
      A  = fmaf(uu, A, xt);
      Mx = fmaxf(fmaf(uu, Mx, xt), 0.f);
      Bc *= uu;
    }
  }
  tA[w * 64 + lane] = A; tB[w * 64 + lane] = Bc; tM[w * 64 + lane] = Mx;
  __syncthreads();

  float pA = 0.f, pM = 0.f;
  for (int s = 0; s < w; ++s) {
    float a = tA[s * 64 + lane], b = tB[s * 64 + lane], mm = tM[s * 64 + lane];
    pA = fmaf(b, pA, a);
    pM = fmaxf(fmaf(b, pM, a), mm);
  }
  float h = fmaxf(pA, pM);

  for (int c0 = 0; c0 < 64; c0 += 16) {
    float vb[16], xb[16];
#pragma unroll
    for (int i = 0; i < 16; ++i) vb[i] = py[(base + c0 + i) * 16384];
#pragma unroll
    for (int i = 0; i < 16; ++i) xb[i] = px[(base + c0 + i) * 16384];
#pragma unroll
    for (int i = 0; i < 16; ++i) {
      float xt = fmaf(vb[i], sc, sh);
      h = fmaxf(fmaf(uu, h, xt), 0.f);
      py[(base + c0 + i) * 16384] = h + xb[i];
    }
  }
}

extern "C" void kernel_launch(void* const* d_in, const int* in_sizes, int n_in,
                              void* d_out, int out_size, void* d_ws, size_t ws_size,
                              hipStream_t stream) {
  if (n_in < 11) return;
  const float* x   = (const float*)d_in[0];
  const float* W1  = (const float*)d_in[1];
  const float* b1  = (const float*)d_in[2];
  const float* g1  = (const float*)d_in[3];
  const float* be1 = (const float*)d_in[4];
  const float* u1  = (const float*)d_in[5];
  const float* W2  = (const float*)d_in[6];
  const float* b2  = (const float*)d_in[7];
  const float* g2  = (const float*)d_in[8];
  const float* be2 = (const float*)d_in[9];
  const float* u2  = (const float*)d_in[10];
  float* out = (float*)d_out;

  char* ws = (char*)d_ws;
  const size_t SZ_HALF = (size_t)M_DIM * C_DIM * sizeof(unsigned short);
  const size_t SZ_W    = (size_t)C_DIM * C_DIM * sizeof(unsigned short);
  unsigned short* Ahi  = (unsigned short*)(ws);             // x split; reused as h1 split
  unsigned short* Alo  = (unsigned short*)(ws + SZ_HALF);
  unsigned short* W1hi = (unsigned short*)(ws + 2 * SZ_HALF);
  unsigned short* W1lo = W1hi + C_DIM * C_DIM;
  unsigned short* W2hi = W1lo + C_DIM * C_DIM;
  unsigned short* W2lo = W2hi + C_DIM * C_DIM;
  float* stats = (float*)(ws + 2 * SZ_HALF + 4 * SZ_W);
  float* sum1 = stats,        *sq1 = stats + 512;
  float* sum2 = stats + 1024, *sq2 = stats + 1536;
  if (ws_size < 2 * SZ_HALF + 4 * SZ_W + 4 * 512 * sizeof(float)) return;

  hipMemsetAsync(stats, 0, 4 * 512 * sizeof(float), stream);

  k_split_all<<<2048, 256, 0, stream>>>(x, W1, W2, Ahi, Alo, W1hi, W1lo, W2hi, W2lo);

  dim3 gemmGrid(256);
  k_gemm<<<gemmGrid, 512, 0, stream>>>(Ahi, Alo, W1hi, W1lo, b1, out, sum1, sq1);
  k_indrnn_split<<<256, 1024, 0, stream>>>(out, sum1, sq1, g1, be1, u1, Ahi, Alo);

  k_gemm<<<gemmGrid, 512, 0, stream>>>(Ahi, Alo, W2hi, W2lo, b2, out, sum2, sq2);
  k_indrnn_res<<<256, 1024, 0, stream>>>(out, x, sum2, sq2, g2, be2, u2);
}